// Round 4
// baseline (539.012 us; speedup 1.0000x reference)
//
#include <hip/hip_runtime.h>
#include <cstdint>
#include <cstddef>

// Problem constants (match reference)
#define BTOT    4096
#define SRCLEN  128
#define INDIM   16
#define HDIM    64
#define SEQLEN  100
#define MEANS_N (BTOT * SEQLEN * 4)   // 1638400

// ---------- helpers ----------
__device__ __forceinline__ float sigmoidf_(float x) { return 1.0f / (1.0f + __expf(-x)); }
__device__ __forceinline__ float tanhf_(float x) {
    float e = __expf(2.0f * x);
    return 1.0f - 2.0f / (e + 1.0f);
}
__device__ __forceinline__ float gelu_exact(float x) {
    return 0.5f * x * (1.0f + erff(x * 0.70710678118654752440f));
}

// ---------- bf16 split helpers (bf16x3 emulated-fp32 MFMA) ----------
typedef __attribute__((ext_vector_type(8))) short s8v;   // 8 bf16 (4 VGPRs) — MFMA A/B frag
typedef __attribute__((ext_vector_type(4))) float f4v;   // 4 fp32 — MFMA C/D frag

__device__ __forceinline__ unsigned short f2bf(float x) {  // RTNE float -> bf16 bits
    unsigned u = __float_as_uint(x);
    unsigned r = (u + 0x7FFFu + ((u >> 16) & 1u)) >> 16;
    return (unsigned short)r;
}
__device__ __forceinline__ float bf2f(unsigned short b) {
    return __uint_as_float(((unsigned)b) << 16);
}
// RTNE hi as masked fp32 bits (1 round, no shift round-trip)
__device__ __forceinline__ unsigned rtne_hi_bits(float x) {
    unsigned u = __float_as_uint(x);
    return (u + 0x7FFFu + ((u >> 16) & 1u)) & 0xFFFF0000u;
}
// full-RTNE split (prologue / weights — accuracy-max, off hot loop)
__device__ __forceinline__ void split2(float4 a, float4 b, s8v& hi, s8v& lo) {
    float v[8] = {a.x, a.y, a.z, a.w, b.x, b.y, b.z, b.w};
    #pragma unroll
    for (int j = 0; j < 8; ++j) {
        unsigned short h = f2bf(v[j]);
        hi[j] = (short)h;
        lo[j] = (short)f2bf(v[j] - bf2f(h));
    }
}
__device__ __forceinline__ void split8(const float* v, s8v& hi, s8v& lo) {
    #pragma unroll
    for (int j = 0; j < 8; ++j) {
        unsigned short h = f2bf(v[j]);
        hi[j] = (short)h;
        lo[j] = (short)f2bf(v[j] - bf2f(h));
    }
}
// fast hot-loop split: RTNE hi + truncated lo (err <= 2^-17 |x|)
__device__ __forceinline__ void split2_fast(float4 a, float4 b, s8v& hi, s8v& lo) {
    float v[8] = {a.x, a.y, a.z, a.w, b.x, b.y, b.z, b.w};
    #pragma unroll
    for (int j = 0; j < 8; ++j) {
        unsigned hb = rtne_hi_bits(v[j]);
        hi[j] = (short)(hb >> 16);
        float lof = v[j] - __uint_as_float(hb);
        lo[j] = (short)(__float_as_uint(lof) >> 16);
    }
}
// fast h split + LDS store
__device__ __forceinline__ void h_split_store(float h, unsigned short* hp, unsigned short* lp) {
    unsigned hb = rtne_hi_bits(h);
    *hp = (unsigned short)(hb >> 16);
    float lof = h - __uint_as_float(hb);
    *lp = (unsigned short)(__float_as_uint(lof) >> 16);
}
__device__ __forceinline__ void load_bfrag(const float* p, s8v& hi, s8v& lo) {
    float4 a = *(const float4*)p;
    float4 b = *(const float4*)(p + 4);
    split2(a, b, hi, lo);
}

#define MFMA16(a, b, c) __builtin_amdgcn_mfma_f32_16x16x32_bf16((a), (b), (c), 0, 0, 0)

// =====================================================================
// Encoder GRU via MFMA (bf16x3), 2 batch-tiles per WG (8 waves, 512 thr):
// waves 0-3 -> tile 0, waves 4-7 -> tile 1 (independent 16-batch groups
// sharing only the WG barrier) => 2 waves/SIMD hide each other's stalls.
// Grid = BTOT/32 = 128 WGs.
// =====================================================================
__global__ __launch_bounds__(512, 1) void enc_mfma_kernel(
    const float* __restrict__ x,
    const float* __restrict__ Wih, const float* __restrict__ bih,
    const float* __restrict__ Whh, const float* __restrict__ bhh,
    float* __restrict__ enc_h)
{
    const int tid  = threadIdx.x;
    const int g    = tid >> 8;         // tile 0/1
    const int lane = tid & 63;
    const int wl   = (tid >> 6) & 3;   // wave-in-tile 0..3
    const int col  = lane & 15;
    const int q    = lane >> 4;
    const int u    = wl * 16 + col;    // gate-local unit 0..63
    const int b0   = blockIdx.x * 32 + g * 16;

    // [tile][buf][batch][k(+8 pad)]
    __shared__ __align__(16) unsigned short hiL[2][2][16][72];
    __shared__ __align__(16) unsigned short loL[2][2][16][72];

    for (int i = tid; i < 2 * 2 * 16 * 72; i += 512) {
        ((unsigned short*)hiL)[i] = 0;
        ((unsigned short*)loL)[i] = 0;
    }

    const s8v z8 = {0, 0, 0, 0, 0, 0, 0, 0};
    const f4v z4 = {0.0f, 0.0f, 0.0f, 0.0f};

    // ---- B fragments (weights) in VGPRs; K: [0,64)=h, [64,80)=x, [80,96)=0
    s8v brh[3], brl[3], bzh[3], bzl[3], bnhh[2], bnhl[2], bnxh, bnxl;
    load_bfrag(Whh + (size_t)u * 64 + q * 8,              brh[0], brl[0]);
    load_bfrag(Whh + (size_t)u * 64 + 32 + q * 8,         brh[1], brl[1]);
    load_bfrag(Whh + (size_t)(64 + u) * 64 + q * 8,       bzh[0], bzl[0]);
    load_bfrag(Whh + (size_t)(64 + u) * 64 + 32 + q * 8,  bzh[1], bzl[1]);
    load_bfrag(Whh + (size_t)(128 + u) * 64 + q * 8,      bnhh[0], bnhl[0]);
    load_bfrag(Whh + (size_t)(128 + u) * 64 + 32 + q * 8, bnhh[1], bnhl[1]);
    if (q < 2) {
        load_bfrag(Wih + (size_t)u * 16 + q * 8,         brh[2], brl[2]);
        load_bfrag(Wih + (size_t)(64 + u) * 16 + q * 8,  bzh[2], bzl[2]);
        load_bfrag(Wih + (size_t)(128 + u) * 16 + q * 8, bnxh, bnxl);
    } else {
        brh[2] = z8; brl[2] = z8; bzh[2] = z8; bzl[2] = z8; bnxh = z8; bnxl = z8;
    }

    const float br   = bih[u] + bhh[u];
    const float bz   = bih[u + 64] + bhh[u + 64];
    const float bnx  = bih[u + 128];
    const float bnh  = bhh[u + 128];

    s8v xh = z8, xl = z8;
    if (q < 2) {
        const float* xp = x + ((size_t)(b0 + col) * SRCLEN + 0) * INDIM + q * 8;
        split2_fast(*(const float4*)xp, *(const float4*)(xp + 4), xh, xl);
    }

    f4v hold = z4;
    __syncthreads();

    int cur = 0;
    for (int t = 0; t < SRCLEN; ++t) {
        // prefetch x_{t+1} (clamped; last-step value split but unused)
        float4 nx0, nx1;
        if (q < 2) {
            const int tt = (t + 1 < SRCLEN) ? (t + 1) : (SRCLEN - 1);
            const float* xp = x + ((size_t)(b0 + col) * SRCLEN + tt) * INDIM + q * 8;
            nx0 = *(const float4*)xp;
            nx1 = *(const float4*)(xp + 4);
        }

        const s8v ah0 = *(const s8v*)&hiL[g][cur][col][q * 8];
        const s8v al0 = *(const s8v*)&loL[g][cur][col][q * 8];
        const s8v ah1 = *(const s8v*)&hiL[g][cur][col][32 + q * 8];
        const s8v al1 = *(const s8v*)&loL[g][cur][col][32 + q * 8];

        f4v accr, accz, accnh, accnx;
        accr  = MFMA16(ah0, brh[0], z4);
        accz  = MFMA16(ah0, bzh[0], z4);
        accnh = MFMA16(ah0, bnhh[0], z4);
        accr  = MFMA16(ah0, brl[0], accr);
        accz  = MFMA16(ah0, bzl[0], accz);
        accnh = MFMA16(ah0, bnhl[0], accnh);
        accr  = MFMA16(al0, brh[0], accr);
        accz  = MFMA16(al0, bzh[0], accz);
        accnh = MFMA16(al0, bnhh[0], accnh);
        accr  = MFMA16(ah1, brh[1], accr);
        accz  = MFMA16(ah1, bzh[1], accz);
        accnh = MFMA16(ah1, bnhh[1], accnh);
        accr  = MFMA16(ah1, brl[1], accr);
        accz  = MFMA16(ah1, bzl[1], accz);
        accnh = MFMA16(ah1, bnhl[1], accnh);
        accr  = MFMA16(al1, brh[1], accr);
        accz  = MFMA16(al1, bzh[1], accz);
        accnh = MFMA16(al1, bnhh[1], accnh);
        accr  = MFMA16(xh, brh[2], accr);
        accz  = MFMA16(xh, bzh[2], accz);
        accnx = MFMA16(xh, bnxh, z4);
        accr  = MFMA16(xh, brl[2], accr);
        accz  = MFMA16(xh, bzl[2], accz);
        accnx = MFMA16(xh, bnxl, accnx);
        accr  = MFMA16(xl, brh[2], accr);
        accz  = MFMA16(xl, bzh[2], accz);
        accnx = MFMA16(xl, bnxh, accnx);

        const int nxt = cur ^ 1;
        unsigned short* hw = &hiL[g][nxt][q * 4][u];
        unsigned short* lw = &loL[g][nxt][q * 4][u];
        #pragma unroll
        for (int i = 0; i < 4; ++i) {
            float r  = sigmoidf_(accr[i] + br);
            float zz = sigmoidf_(accz[i] + bz);
            float n  = tanhf_(accnx[i] + bnx + r * (accnh[i] + bnh));
            float h  = (1.0f - zz) * n + zz * hold[i];
            hold[i] = h;
            h_split_store(h, hw + i * 72, lw + i * 72);
        }
        __syncthreads();

        if (q < 2) split2_fast(nx0, nx1, xh, xl);
        cur ^= 1;
    }

    #pragma unroll
    for (int i = 0; i < 4; ++i)
        enc_h[(size_t)(b0 + q * 4 + i) * HDIM + u] = hold[i];
}

// =====================================================================
// Decoder GRU via MFMA, out-projection folded into the recurrence,
// 2 batch-tiles per WG (8 waves).  Grid = BTOT/32 = 128 WGs.
// =====================================================================
__global__ __launch_bounds__(512, 1) void dec_mfma_kernel(
    const float* __restrict__ trg,
    const float* __restrict__ Wih, const float* __restrict__ bih,
    const float* __restrict__ Whh, const float* __restrict__ bhh,
    const float* __restrict__ outW, const float* __restrict__ outb,
    const float* __restrict__ embW, const float* __restrict__ embb,
    const float* __restrict__ enc_h,
    float* __restrict__ dec_o)
{
    const int tid  = threadIdx.x;
    const int g    = tid >> 8;         // tile 0/1
    const int lane = tid & 63;
    const int wl   = (tid >> 6) & 3;   // wave-in-tile
    const int col  = lane & 15;
    const int q    = lane >> 4;
    const int u    = wl * 16 + col;
    const int b0   = blockIdx.x * 32 + g * 16;

    __shared__ __align__(16) unsigned short hiL[2][2][16][72];
    __shared__ __align__(16) unsigned short loL[2][2][16][72];
    __shared__ float outW_l[16][64];       // shared across tiles
    __shared__ float init_l[2][16][16];    // per tile

    // ---- stage LDS ----
    for (int i = tid; i < 16 * 64; i += 512) outW_l[i >> 6][i & 63] = outW[i];
    {
        int g3 = tid >> 8, b = (tid >> 4) & 15, jj = tid & 15;
        float s = embb[jj];
        #pragma unroll
        for (int s4 = 0; s4 < 4; ++s4)
            s = fmaf(embW[jj * 4 + s4], trg[(size_t)(blockIdx.x * 32 + g3 * 16 + b) * 4 + s4], s);
        init_l[g3][b][jj] = s;
    }
    {
        int idx = tid * 4;                  // 2048 floats of h0 for this WG
        int g2 = idx >> 10, bb = (idx >> 6) & 15, uu = idx & 63;
        float4 v = *(const float4*)(enc_h + (size_t)(blockIdx.x * 32 + g2 * 16 + bb) * HDIM + uu);
        float vv[4] = {v.x, v.y, v.z, v.w};
        #pragma unroll
        for (int j = 0; j < 4; ++j) {
            unsigned short hh = f2bf(vv[j]);
            hiL[g2][0][bb][uu + j] = hh;
            loL[g2][0][bb][uu + j] = f2bf(vv[j] - bf2f(hh));
        }
    }
    f4v hold;
    #pragma unroll
    for (int i = 0; i < 4; ++i)
        hold[i] = enc_h[(size_t)(b0 + q * 4 + i) * HDIM + u];

    __syncthreads();

    const f4v z4 = {0.0f, 0.0f, 0.0f, 0.0f};

    // ---- fp32 weight rows for this lane's k-slice ----
    float wh_r[16], wh_z[16], wh_n[16];
    #pragma unroll
    for (int c = 0; c < 2; ++c)
        #pragma unroll
        for (int jj = 0; jj < 8; ++jj) {
            int k = c * 32 + q * 8 + jj;
            wh_r[c * 8 + jj] = Whh[(size_t)u * 64 + k];
            wh_z[c * 8 + jj] = Whh[(size_t)(64 + u) * 64 + k];
            wh_n[c * 8 + jj] = Whh[(size_t)(128 + u) * 64 + k];
        }
    float wi_r[16], wi_z[16], wi_n[16];
    #pragma unroll
    for (int j = 0; j < 16; ++j) {
        wi_r[j] = Wih[(size_t)u * 16 + j];
        wi_z[j] = Wih[(size_t)(64 + u) * 16 + j];
        wi_n[j] = Wih[(size_t)(128 + u) * 16 + j];
    }

    // ---- Wcomb = Wih @ outW; merge into r/z; i_n separate ----
    float m_r[16], m_z[16], c_in[16];
    #pragma unroll
    for (int c = 0; c < 2; ++c)
        #pragma unroll
        for (int jj = 0; jj < 8; ++jj) {
            int k = c * 32 + q * 8 + jj;
            float sr = 0.0f, sz = 0.0f, sn = 0.0f;
            #pragma unroll
            for (int j = 0; j < 16; ++j) {
                float ow = outW_l[j][k];
                sr = fmaf(wi_r[j], ow, sr);
                sz = fmaf(wi_z[j], ow, sz);
                sn = fmaf(wi_n[j], ow, sn);
            }
            m_r[c * 8 + jj]  = wh_r[c * 8 + jj] + sr;
            m_z[c * 8 + jj]  = wh_z[c * 8 + jj] + sz;
            c_in[c * 8 + jj] = sn;
        }

    // ---- B-frags ----
    s8v mrh[2], mrl[2], mzh[2], mzl[2], cinh[2], cinl[2], hnh[2], hnl[2];
    split8(m_r,      mrh[0],  mrl[0]);  split8(m_r + 8,  mrh[1],  mrl[1]);
    split8(m_z,      mzh[0],  mzl[0]);  split8(m_z + 8,  mzh[1],  mzl[1]);
    split8(c_in,     cinh[0], cinl[0]); split8(c_in + 8, cinh[1], cinl[1]);
    split8(wh_n,     hnh[0],  hnl[0]);  split8(wh_n + 8, hnh[1],  hnl[1]);
    s8v r0h[2], r0l[2], z0h[2], z0l[2];
    split8(wh_r, r0h[0], r0l[0]); split8(wh_r + 8, r0h[1], r0l[1]);
    split8(wh_z, z0h[0], z0l[0]); split8(wh_z + 8, z0h[1], z0l[1]);
    s8v owh[2], owl[2];
    {
        float ov[16];
        #pragma unroll
        for (int c = 0; c < 2; ++c)
            #pragma unroll
            for (int jj = 0; jj < 8; ++jj)
                ov[c * 8 + jj] = outW_l[col][c * 32 + q * 8 + jj];
        split8(ov, owh[0], owl[0]); split8(ov + 8, owh[1], owl[1]);
    }

    // ---- folded biases ----
    float b_r = bhh[u] + bih[u];
    float b_z = bhh[u + 64] + bih[u + 64];
    float b_in = bih[u + 128];
    const float b_hn = bhh[u + 128];
    #pragma unroll
    for (int j = 0; j < 16; ++j) {
        float obj = outb[j];
        b_r  = fmaf(obj, wi_r[j], b_r);
        b_z  = fmaf(obj, wi_z[j], b_z);
        b_in = fmaf(obj, wi_n[j], b_in);
    }
    const float ob = outb[col];

    // ---- gi0 from init_in ----
    float g_r[4], g_z[4], g_n[4];
    #pragma unroll
    for (int i = 0; i < 4; ++i) {
        float sr = bih[u] + bhh[u];
        float sz = bih[u + 64] + bhh[u + 64];
        float sn = bih[u + 128];
        #pragma unroll
        for (int j = 0; j < 16; ++j) {
            float iv = init_l[g][q * 4 + i][j];
            sr = fmaf(wi_r[j], iv, sr);
            sz = fmaf(wi_z[j], iv, sz);
            sn = fmaf(wi_n[j], iv, sn);
        }
        g_r[i] = sr; g_z[i] = sz; g_n[i] = sn;
    }

    // ---- step 0 ----
    {
        const s8v ah0 = *(const s8v*)&hiL[g][0][col][q * 8];
        const s8v al0 = *(const s8v*)&loL[g][0][col][q * 8];
        const s8v ah1 = *(const s8v*)&hiL[g][0][col][32 + q * 8];
        const s8v al1 = *(const s8v*)&loL[g][0][col][32 + q * 8];
        f4v ar, az, ahn;
        ar  = MFMA16(ah0, r0h[0], z4);
        az  = MFMA16(ah0, z0h[0], z4);
        ahn = MFMA16(ah0, hnh[0], z4);
        ar  = MFMA16(ah0, r0l[0], ar);
        az  = MFMA16(ah0, z0l[0], az);
        ahn = MFMA16(ah0, hnl[0], ahn);
        ar  = MFMA16(al0, r0h[0], ar);
        az  = MFMA16(al0, z0h[0], az);
        ahn = MFMA16(al0, hnh[0], ahn);
        ar  = MFMA16(ah1, r0h[1], ar);
        az  = MFMA16(ah1, z0h[1], az);
        ahn = MFMA16(ah1, hnh[1], ahn);
        ar  = MFMA16(ah1, r0l[1], ar);
        az  = MFMA16(ah1, z0l[1], az);
        ahn = MFMA16(ah1, hnl[1], ahn);
        ar  = MFMA16(al1, r0h[1], ar);
        az  = MFMA16(al1, z0h[1], az);
        ahn = MFMA16(al1, hnh[1], ahn);
        unsigned short* hw = &hiL[g][1][q * 4][u];
        unsigned short* lw = &loL[g][1][q * 4][u];
        #pragma unroll
        for (int i = 0; i < 4; ++i) {
            float r  = sigmoidf_(ar[i] + g_r[i]);
            float zz = sigmoidf_(az[i] + g_z[i]);
            float n  = tanhf_(g_n[i] + r * (ahn[i] + b_hn));
            float h  = (1.0f - zz) * n + zz * hold[i];
            hold[i] = h;
            h_split_store(h, hw + i * 72, lw + i * 72);
        }
        __syncthreads();
    }

    // ---- steps 1..99 (merged weights); o_{t-1} by wave-in-tile 0 ----
    for (int t = 1; t < SEQLEN; ++t) {
        const int cur = t & 1;
        const s8v ah0 = *(const s8v*)&hiL[g][cur][col][q * 8];
        const s8v al0 = *(const s8v*)&loL[g][cur][col][q * 8];
        const s8v ah1 = *(const s8v*)&hiL[g][cur][col][32 + q * 8];
        const s8v al1 = *(const s8v*)&loL[g][cur][col][32 + q * 8];

        if (wl == 0) {  // o_{t-1} = h_t @ outW^T + outb
            f4v oa;
            oa = MFMA16(ah0, owh[0], z4);
            oa = MFMA16(ah0, owl[0], oa);
            oa = MFMA16(al0, owh[0], oa);
            oa = MFMA16(ah1, owh[1], oa);
            oa = MFMA16(ah1, owl[1], oa);
            oa = MFMA16(al1, owh[1], oa);
            #pragma unroll
            for (int i = 0; i < 4; ++i)
                dec_o[(((size_t)(b0 + q * 4 + i) * SEQLEN) + (t - 1)) * INDIM + col] = oa[i] + ob;
        }

        f4v ar, az, ain, ahn;
        ar  = MFMA16(ah0, mrh[0], z4);
        az  = MFMA16(ah0, mzh[0], z4);
        ain = MFMA16(ah0, cinh[0], z4);
        ahn = MFMA16(ah0, hnh[0], z4);
        ar  = MFMA16(ah0, mrl[0], ar);
        az  = MFMA16(ah0, mzl[0], az);
        ain = MFMA16(ah0, cinl[0], ain);
        ahn = MFMA16(ah0, hnl[0], ahn);
        ar  = MFMA16(al0, mrh[0], ar);
        az  = MFMA16(al0, mzh[0], az);
        ain = MFMA16(al0, cinh[0], ain);
        ahn = MFMA16(al0, hnh[0], ahn);
        ar  = MFMA16(ah1, mrh[1], ar);
        az  = MFMA16(ah1, mzh[1], az);
        ain = MFMA16(ah1, cinh[1], ain);
        ahn = MFMA16(ah1, hnh[1], ahn);
        ar  = MFMA16(ah1, mrl[1], ar);
        az  = MFMA16(ah1, mzl[1], az);
        ain = MFMA16(ah1, cinl[1], ain);
        ahn = MFMA16(ah1, hnl[1], ahn);
        ar  = MFMA16(al1, mrh[1], ar);
        az  = MFMA16(al1, mzh[1], az);
        ain = MFMA16(al1, cinh[1], ain);
        ahn = MFMA16(al1, hnh[1], ahn);

        const int nxt = cur ^ 1;
        unsigned short* hw = &hiL[g][nxt][q * 4][u];
        unsigned short* lw = &loL[g][nxt][q * 4][u];
        #pragma unroll
        for (int i = 0; i < 4; ++i) {
            float r  = sigmoidf_(ar[i] + b_r);
            float zz = sigmoidf_(az[i] + b_z);
            float n  = tanhf_(ain[i] + b_in + r * (ahn[i] + b_hn));
            float h  = (1.0f - zz) * n + zz * hold[i];
            hold[i] = h;
            h_split_store(h, hw + i * 72, lw + i * 72);
        }
        __syncthreads();
    }

    // ---- epilogue: o_99 from buf 0 ----
    if (wl == 0) {
        const s8v ah0 = *(const s8v*)&hiL[g][0][col][q * 8];
        const s8v al0 = *(const s8v*)&loL[g][0][col][q * 8];
        const s8v ah1 = *(const s8v*)&hiL[g][0][col][32 + q * 8];
        const s8v al1 = *(const s8v*)&loL[g][0][col][32 + q * 8];
        f4v oa;
        oa = MFMA16(ah0, owh[0], z4);
        oa = MFMA16(ah0, owl[0], oa);
        oa = MFMA16(al0, owh[0], oa);
        oa = MFMA16(ah1, owh[1], oa);
        oa = MFMA16(ah1, owl[1], oa);
        oa = MFMA16(al1, owh[1], oa);
        #pragma unroll
        for (int i = 0; i < 4; ++i)
            dec_o[(((size_t)(b0 + q * 4 + i) * SEQLEN) + (SEQLEN - 1)) * INDIM + col] = oa[i] + ob;
    }
}

// =====================================================================
// Heads: 409600 independent rows; one thread per row. (unchanged)
// =====================================================================
__global__ void heads_kernel(
    const float* __restrict__ dec_o,
    const float* __restrict__ mW1, const float* __restrict__ mb1,
    const float* __restrict__ mW2, const float* __restrict__ mb2,
    const float* __restrict__ cW1, const float* __restrict__ cb1,
    const float* __restrict__ cW2, const float* __restrict__ cb2,
    float* __restrict__ out)
{
    const size_t r = (size_t)blockIdx.x * 256 + threadIdx.x;  // 0..409599

    float o16[16];
    {
        const float4* op = (const float4*)(dec_o + r * 16);
        #pragma unroll
        for (int c = 0; c < 4; ++c) {
            float4 v = op[c];
            o16[4 * c + 0] = v.x; o16[4 * c + 1] = v.y;
            o16[4 * c + 2] = v.z; o16[4 * c + 3] = v.w;
        }
    }

    float m[4], cv[10];
    #pragma unroll
    for (int j = 0; j < 4; ++j)  m[j]  = mb2[j];
    #pragma unroll
    for (int j = 0; j < 10; ++j) cv[j] = cb2[j];

    #pragma unroll 8
    for (int hu = 0; hu < 64; ++hu) {
        const float* w1m = mW1 + hu * 16;
        float hm = mb1[hu];
        #pragma unroll
        for (int i = 0; i < 16; ++i) hm = fmaf(w1m[i], o16[i], hm);
        float gm = gelu_exact(hm);
        #pragma unroll
        for (int j = 0; j < 4; ++j) m[j] = fmaf(mW2[j * 64 + hu], gm, m[j]);

        const float* w1c = cW1 + hu * 16;
        float hc = cb1[hu];
        #pragma unroll
        for (int i = 0; i < 16; ++i) hc = fmaf(w1c[i], o16[i], hc);
        float gc = gelu_exact(hc);
        #pragma unroll
        for (int j = 0; j < 10; ++j) cv[j] = fmaf(cW2[j * 64 + hu], gc, cv[j]);
    }

    m[2] = fminf(fmaxf(m[2], -1.0f), 1.0f);
    m[3] = fminf(fmaxf(m[3], -1.0f), 1.0f);

    float* means = out;
    float* covs  = out + MEANS_N;
    #pragma unroll
    for (int j = 0; j < 4; ++j)  means[r * 4 + j]  = m[j];
    #pragma unroll
    for (int j = 0; j < 10; ++j) covs[r * 10 + j]  = cv[j];
}

// =====================================================================
extern "C" void kernel_launch(void* const* d_in, const int* in_sizes, int n_in,
                              void* d_out, int out_size, void* d_ws, size_t ws_size,
                              hipStream_t stream)
{
    const float* x    = (const float*)d_in[0];
    const float* trg  = (const float*)d_in[1];
    const float* eWih = (const float*)d_in[2];
    const float* ebih = (const float*)d_in[3];
    const float* eWhh = (const float*)d_in[4];
    const float* ebhh = (const float*)d_in[5];
    const float* dWih = (const float*)d_in[6];
    const float* dbih = (const float*)d_in[7];
    const float* dWhh = (const float*)d_in[8];
    const float* dbhh = (const float*)d_in[9];
    const float* outW = (const float*)d_in[10];
    const float* outb = (const float*)d_in[11];
    const float* embW = (const float*)d_in[12];
    const float* embb = (const float*)d_in[13];
    const float* mW1  = (const float*)d_in[14];
    const float* mb1  = (const float*)d_in[15];
    const float* mW2  = (const float*)d_in[16];
    const float* mb2  = (const float*)d_in[17];
    const float* cW1  = (const float*)d_in[18];
    const float* cb1  = (const float*)d_in[19];
    const float* cW2  = (const float*)d_in[20];
    const float* cb2  = (const float*)d_in[21];

    float* ws    = (float*)d_ws;
    float* enc_h = ws;                          // 4096*64      = 262144 floats
    float* dec_o = ws + (size_t)BTOT * HDIM;    // 4096*100*16  = 6553600 floats
    float* outp  = (float*)d_out;

    enc_mfma_kernel<<<dim3(BTOT / 32), dim3(512), 0, stream>>>(x, eWih, ebih, eWhh, ebhh, enc_h);
    dec_mfma_kernel<<<dim3(BTOT / 32), dim3(512), 0, stream>>>(trg, dWih, dbih, dWhh, dbhh,
                                                               outW, outb, embW, embb, enc_h, dec_o);
    heads_kernel<<<dim3((BTOT * SEQLEN) / 256), dim3(256), 0, stream>>>(
        dec_o, mW1, mb1, mW2, mb2, cW1, cb1, cW2, cb2, outp);
}

// Round 5
// 437.431 us; speedup vs baseline: 1.2322x; 1.2322x over previous
//
#include <hip/hip_runtime.h>
#include <cstdint>
#include <cstddef>

// Problem constants (match reference)
#define BTOT    4096
#define SRCLEN  128
#define INDIM   16
#define HDIM    64
#define SEQLEN  100
#define MEANS_N (BTOT * SEQLEN * 4)   // 1638400

// ---------- helpers ----------
__device__ __forceinline__ float sigmoidf_(float x) { return 1.0f / (1.0f + __expf(-x)); }
__device__ __forceinline__ float tanhf_(float x) {
    float e = __expf(2.0f * x);
    return 1.0f - 2.0f / (e + 1.0f);
}
__device__ __forceinline__ float gelu_exact(float x) {
    return 0.5f * x * (1.0f + erff(x * 0.70710678118654752440f));
}

// lgkm-only barrier: drains LDS ops but NOT outstanding global loads/stores,
// so in-loop prefetch loads / result stores never stall the barrier (the
// compiler's __syncthreads always drains vmcnt(0) — that's the stall we avoid).
__device__ __forceinline__ void lgkm_barrier() {
    asm volatile("s_waitcnt lgkmcnt(0)" ::: "memory");
    __builtin_amdgcn_s_barrier();
}

// ---------- bf16 split helpers (bf16x3 emulated-fp32 MFMA) ----------
typedef __attribute__((ext_vector_type(8))) short s8v;   // 8 bf16 (4 VGPRs) — MFMA A/B frag
typedef __attribute__((ext_vector_type(4))) float f4v;   // 4 fp32 — MFMA C/D frag

__device__ __forceinline__ unsigned short f2bf(float x) {  // RTNE float -> bf16 bits
    unsigned u = __float_as_uint(x);
    unsigned r = (u + 0x7FFFu + ((u >> 16) & 1u)) >> 16;
    return (unsigned short)r;
}
__device__ __forceinline__ float bf2f(unsigned short b) {
    return __uint_as_float(((unsigned)b) << 16);
}
__device__ __forceinline__ unsigned rtne_hi_bits(float x) {
    unsigned u = __float_as_uint(x);
    return (u + 0x7FFFu + ((u >> 16) & 1u)) & 0xFFFF0000u;
}
// full-RTNE split (prologue / weights)
__device__ __forceinline__ void split2(float4 a, float4 b, s8v& hi, s8v& lo) {
    float v[8] = {a.x, a.y, a.z, a.w, b.x, b.y, b.z, b.w};
    #pragma unroll
    for (int j = 0; j < 8; ++j) {
        unsigned short h = f2bf(v[j]);
        hi[j] = (short)h;
        lo[j] = (short)f2bf(v[j] - bf2f(h));
    }
}
__device__ __forceinline__ void split8(const float* v, s8v& hi, s8v& lo) {
    #pragma unroll
    for (int j = 0; j < 8; ++j) {
        unsigned short h = f2bf(v[j]);
        hi[j] = (short)h;
        lo[j] = (short)f2bf(v[j] - bf2f(h));
    }
}
// fast hot-loop split: RTNE hi + truncated lo (err <= 2^-17 |x|)
__device__ __forceinline__ void split2_fast(float4 a, float4 b, s8v& hi, s8v& lo) {
    float v[8] = {a.x, a.y, a.z, a.w, b.x, b.y, b.z, b.w};
    #pragma unroll
    for (int j = 0; j < 8; ++j) {
        unsigned hb = rtne_hi_bits(v[j]);
        hi[j] = (short)(hb >> 16);
        float lof = v[j] - __uint_as_float(hb);
        lo[j] = (short)(__float_as_uint(lof) >> 16);
    }
}
__device__ __forceinline__ void h_split_store(float h, unsigned short* hp, unsigned short* lp) {
    unsigned hb = rtne_hi_bits(h);
    *hp = (unsigned short)(hb >> 16);
    float lof = h - __uint_as_float(hb);
    *lp = (unsigned short)(__float_as_uint(lof) >> 16);
}
__device__ __forceinline__ void load_bfrag(const float* p, s8v& hi, s8v& lo) {
    float4 a = *(const float4*)p;
    float4 b = *(const float4*)(p + 4);
    split2(a, b, hi, lo);
}

#define MFMA16(a, b, c) __builtin_amdgcn_mfma_f32_16x16x32_bf16((a), (b), (c), 0, 0, 0)

// =====================================================================
// Encoder GRU, G/N wave split.  Grid 256 WGs x 512 threads (8 waves):
//   G-waves (0-3): r,z gates — 18 MFMA + 2 sigmoids -> rsL/zsL
//   N-waves (4-7): n-gate — 9 MFMA + tanh + h update + h split-store
// SIMD s hosts (G_s, N_s): complementary pipes overlap. 2 lgkm barriers/step.
// =====================================================================
__global__ __launch_bounds__(512, 2) void enc_mfma_kernel(
    const float* __restrict__ x,
    const float* __restrict__ Wih, const float* __restrict__ bih,
    const float* __restrict__ Whh, const float* __restrict__ bhh,
    float* __restrict__ enc_h)
{
    const int tid  = threadIdx.x;
    const int lane = tid & 63;
    const int wl   = tid >> 6;       // 0..7
    const bool isG = (wl < 4);
    const int w4   = isG ? wl : (wl - 4);
    const int col  = lane & 15;
    const int q    = lane >> 4;
    const int u    = w4 * 16 + col;  // gate-local unit 0..63
    const int b0   = blockIdx.x * 16;

    __shared__ __align__(16) unsigned short hiL[2][16][72];
    __shared__ __align__(16) unsigned short loL[2][16][72];
    __shared__ float rsL[16][66];    // stride 66 -> 2-way (free) banks
    __shared__ float zsL[16][66];

    for (int i = tid; i < 16 * 72; i += 512) {   // zero buf 0 (h0 = 0)
        ((unsigned short*)hiL)[i] = 0;
        ((unsigned short*)loL)[i] = 0;
    }

    const s8v z8 = {0, 0, 0, 0, 0, 0, 0, 0};
    const f4v z4 = {0.0f, 0.0f, 0.0f, 0.0f};

    // B-frags: G: b1=r, b2=z (chunks: h[0:32), h[32:64), x). N: b1=n (b1[2]=nx).
    s8v b1h[3], b1l[3], b2h[3], b2l[3];
    #pragma unroll
    for (int c = 0; c < 3; ++c) { b1h[c] = z8; b1l[c] = z8; b2h[c] = z8; b2l[c] = z8; }
    float bias1 = 0.0f, bias2 = 0.0f, bnx = 0.0f, bnh = 0.0f;

    if (isG) {
        load_bfrag(Whh + (size_t)u * 64 + q * 8,             b1h[0], b1l[0]);
        load_bfrag(Whh + (size_t)u * 64 + 32 + q * 8,        b1h[1], b1l[1]);
        load_bfrag(Whh + (size_t)(64 + u) * 64 + q * 8,      b2h[0], b2l[0]);
        load_bfrag(Whh + (size_t)(64 + u) * 64 + 32 + q * 8, b2h[1], b2l[1]);
        if (q < 2) {
            load_bfrag(Wih + (size_t)u * 16 + q * 8,        b1h[2], b1l[2]);
            load_bfrag(Wih + (size_t)(64 + u) * 16 + q * 8, b2h[2], b2l[2]);
        }
        bias1 = bih[u] + bhh[u];
        bias2 = bih[u + 64] + bhh[u + 64];
    } else {
        load_bfrag(Whh + (size_t)(128 + u) * 64 + q * 8,      b1h[0], b1l[0]);
        load_bfrag(Whh + (size_t)(128 + u) * 64 + 32 + q * 8, b1h[1], b1l[1]);
        if (q < 2)
            load_bfrag(Wih + (size_t)(128 + u) * 16 + q * 8,  b1h[2], b1l[2]);  // nx
        bnx = bih[u + 128];
        bnh = bhh[u + 128];
    }

    s8v xh = z8, xl = z8;
    if (q < 2) {
        const float* xp = x + ((size_t)(b0 + col) * SRCLEN + 0) * INDIM + q * 8;
        split2_fast(*(const float4*)xp, *(const float4*)(xp + 4), xh, xl);
    }

    f4v hold = z4;   // N-waves: h_old for slots (batch q*4+i, unit u)
    __syncthreads();

    int cur = 0;
    for (int t = 0; t < SRCLEN; ++t) {
        float4 nx0, nx1;
        if (q < 2) {   // clamped prefetch (never drained at barrier: lgkm-only)
            const int tt = (t + 1 < SRCLEN) ? (t + 1) : (SRCLEN - 1);
            const float* xp = x + ((size_t)(b0 + col) * SRCLEN + tt) * INDIM + q * 8;
            nx0 = *(const float4*)xp;
            nx1 = *(const float4*)(xp + 4);
        }

        const s8v ah0 = *(const s8v*)&hiL[cur][col][q * 8];
        const s8v al0 = *(const s8v*)&loL[cur][col][q * 8];
        const s8v ah1 = *(const s8v*)&hiL[cur][col][32 + q * 8];
        const s8v al1 = *(const s8v*)&loL[cur][col][32 + q * 8];

        f4v anh = z4, anx = z4;
        if (isG) {
            f4v a1, a2;
            a1 = MFMA16(ah0, b1h[0], z4);  a2 = MFMA16(ah0, b2h[0], z4);
            a1 = MFMA16(ah0, b1l[0], a1);  a2 = MFMA16(ah0, b2l[0], a2);
            a1 = MFMA16(al0, b1h[0], a1);  a2 = MFMA16(al0, b2h[0], a2);
            a1 = MFMA16(ah1, b1h[1], a1);  a2 = MFMA16(ah1, b2h[1], a2);
            a1 = MFMA16(ah1, b1l[1], a1);  a2 = MFMA16(ah1, b2l[1], a2);
            a1 = MFMA16(al1, b1h[1], a1);  a2 = MFMA16(al1, b2h[1], a2);
            a1 = MFMA16(xh,  b1h[2], a1);  a2 = MFMA16(xh,  b2h[2], a2);
            a1 = MFMA16(xh,  b1l[2], a1);  a2 = MFMA16(xh,  b2l[2], a2);
            a1 = MFMA16(xl,  b1h[2], a1);  a2 = MFMA16(xl,  b2h[2], a2);
            #pragma unroll
            for (int i = 0; i < 4; ++i) {
                rsL[q * 4 + i][u] = sigmoidf_(a1[i] + bias1);
                zsL[q * 4 + i][u] = sigmoidf_(a2[i] + bias2);
            }
        } else {
            anh = MFMA16(ah0, b1h[0], z4);
            anh = MFMA16(ah0, b1l[0], anh);
            anh = MFMA16(al0, b1h[0], anh);
            anh = MFMA16(ah1, b1h[1], anh);
            anh = MFMA16(ah1, b1l[1], anh);
            anh = MFMA16(al1, b1h[1], anh);
            anx = MFMA16(xh, b1h[2], z4);
            anx = MFMA16(xh, b1l[2], anx);
            anx = MFMA16(xl, b1h[2], anx);
        }
        lgkm_barrier();   // rs/zs ready
        const int nxt = cur ^ 1;
        if (!isG) {
            unsigned short* hw = &hiL[nxt][q * 4][u];
            unsigned short* lw = &loL[nxt][q * 4][u];
            #pragma unroll
            for (int i = 0; i < 4; ++i) {
                float rs = rsL[q * 4 + i][u];
                float zs = zsL[q * 4 + i][u];
                float n  = tanhf_(anx[i] + bnx + rs * (anh[i] + bnh));
                float h  = (1.0f - zs) * n + zs * hold[i];
                hold[i]  = h;
                h_split_store(h, hw + i * 72, lw + i * 72);
            }
        }
        lgkm_barrier();   // h_{t+1} ready
        if (q < 2) split2_fast(nx0, nx1, xh, xl);
        cur = nxt;
    }

    if (!isG) {
        #pragma unroll
        for (int i = 0; i < 4; ++i)
            enc_h[(size_t)(b0 + q * 4 + i) * HDIM + u] = hold[i];
    }
}

// =====================================================================
// Decoder GRU, G/N wave split + out-projection folded (Wcomb = Wih@outW
// merged into r/z; i_n kept separate).  N-wave 3 (wl==7) additionally
// computes o_{t-1} (+6 MFMA) and streams it to dec_o (stores never drained
// at the lgkm-only barriers).  Grid 256 WGs x 512 threads.
// =====================================================================
__global__ __launch_bounds__(512, 2) void dec_mfma_kernel(
    const float* __restrict__ trg,
    const float* __restrict__ Wih, const float* __restrict__ bih,
    const float* __restrict__ Whh, const float* __restrict__ bhh,
    const float* __restrict__ outW, const float* __restrict__ outb,
    const float* __restrict__ embW, const float* __restrict__ embb,
    const float* __restrict__ enc_h,
    float* __restrict__ dec_o)
{
    const int tid  = threadIdx.x;
    const int lane = tid & 63;
    const int wl   = tid >> 6;
    const bool isG = (wl < 4);
    const int w4   = isG ? wl : (wl - 4);
    const int col  = lane & 15;
    const int q    = lane >> 4;
    const int u    = w4 * 16 + col;
    const int b0   = blockIdx.x * 16;

    __shared__ __align__(16) unsigned short hiL[2][16][72];
    __shared__ __align__(16) unsigned short loL[2][16][72];
    __shared__ float rsL[16][66];
    __shared__ float zsL[16][66];
    __shared__ float outW_l[16][64];
    __shared__ float init_l[16][16];

    // ---- stage LDS ----
    for (int i = tid; i < 16 * 64; i += 512) outW_l[i >> 6][i & 63] = outW[i];
    if (tid < 256) {
        int b = tid >> 4, jj = tid & 15;
        float s = embb[jj];
        #pragma unroll
        for (int s4 = 0; s4 < 4; ++s4)
            s = fmaf(embW[jj * 4 + s4], trg[(size_t)(b0 + b) * 4 + s4], s);
        init_l[b][jj] = s;
    }
    if (tid < 256) {
        int idx = tid * 4;
        int bb = idx >> 6, uu = idx & 63;
        float4 v = *(const float4*)(enc_h + (size_t)(b0 + bb) * HDIM + uu);
        float vv[4] = {v.x, v.y, v.z, v.w};
        #pragma unroll
        for (int j = 0; j < 4; ++j) {
            unsigned short hh = f2bf(vv[j]);
            hiL[0][bb][uu + j] = hh;
            loL[0][bb][uu + j] = f2bf(vv[j] - bf2f(hh));
        }
    }
    __syncthreads();

    const s8v z8 = {0, 0, 0, 0, 0, 0, 0, 0};
    const f4v z4 = {0.0f, 0.0f, 0.0f, 0.0f};

    // steady frags: G: w1=m_r, w2=m_z ; N: w1=c_in, w2=wh_n
    s8v w1h[2], w1l[2], w2h[2], w2l[2];
    // step-0 frags (G only): s01=wh_r, s02=wh_z
    s8v s01h[2], s01l[2], s02h[2], s02l[2];
    s8v owh[2], owl[2];
    #pragma unroll
    for (int c = 0; c < 2; ++c) {
        w1h[c] = z8; w1l[c] = z8; w2h[c] = z8; w2l[c] = z8;
        s01h[c] = z8; s01l[c] = z8; s02h[c] = z8; s02l[c] = z8;
        owh[c] = z8; owl[c] = z8;
    }
    float bias1 = 0, bias2 = 0, b_in = 0, b_hn = 0, ob = 0;
    float g1[4] = {0, 0, 0, 0}, g2[4] = {0, 0, 0, 0}, g3[4] = {0, 0, 0, 0};
    f4v hold = z4;

    if (isG) {
        float wh_1[16], wh_2[16], wi_1[16], wi_2[16];
        #pragma unroll
        for (int c = 0; c < 2; ++c)
            #pragma unroll
            for (int jj = 0; jj < 8; ++jj) {
                int k = c * 32 + q * 8 + jj;
                wh_1[c * 8 + jj] = Whh[(size_t)u * 64 + k];
                wh_2[c * 8 + jj] = Whh[(size_t)(64 + u) * 64 + k];
            }
        #pragma unroll
        for (int j = 0; j < 16; ++j) {
            wi_1[j] = Wih[(size_t)u * 16 + j];
            wi_2[j] = Wih[(size_t)(64 + u) * 16 + j];
        }
        float m1[16], m2[16];
        #pragma unroll
        for (int c = 0; c < 2; ++c)
            #pragma unroll
            for (int jj = 0; jj < 8; ++jj) {
                int k = c * 32 + q * 8 + jj;
                float s1 = 0.0f, s2 = 0.0f;
                #pragma unroll
                for (int j = 0; j < 16; ++j) {
                    float ow = outW_l[j][k];
                    s1 = fmaf(wi_1[j], ow, s1);
                    s2 = fmaf(wi_2[j], ow, s2);
                }
                m1[c * 8 + jj] = wh_1[c * 8 + jj] + s1;
                m2[c * 8 + jj] = wh_2[c * 8 + jj] + s2;
            }
        split8(m1,     w1h[0], w1l[0]); split8(m1 + 8, w1h[1], w1l[1]);
        split8(m2,     w2h[0], w2l[0]); split8(m2 + 8, w2h[1], w2l[1]);
        split8(wh_1,     s01h[0], s01l[0]); split8(wh_1 + 8, s01h[1], s01l[1]);
        split8(wh_2,     s02h[0], s02l[0]); split8(wh_2 + 8, s02h[1], s02l[1]);
        bias1 = bhh[u] + bih[u];
        bias2 = bhh[u + 64] + bih[u + 64];
        #pragma unroll
        for (int j = 0; j < 16; ++j) {
            bias1 = fmaf(outb[j], wi_1[j], bias1);
            bias2 = fmaf(outb[j], wi_2[j], bias2);
        }
        #pragma unroll
        for (int i = 0; i < 4; ++i) {
            float sr = bih[u] + bhh[u];
            float sz = bih[u + 64] + bhh[u + 64];
            #pragma unroll
            for (int j = 0; j < 16; ++j) {
                float iv = init_l[q * 4 + i][j];
                sr = fmaf(wi_1[j], iv, sr);
                sz = fmaf(wi_2[j], iv, sz);
            }
            g1[i] = sr; g2[i] = sz;
        }
    } else {
        float wh_n[16], wi_n[16], cin[16];
        #pragma unroll
        for (int c = 0; c < 2; ++c)
            #pragma unroll
            for (int jj = 0; jj < 8; ++jj) {
                int k = c * 32 + q * 8 + jj;
                wh_n[c * 8 + jj] = Whh[(size_t)(128 + u) * 64 + k];
            }
        #pragma unroll
        for (int j = 0; j < 16; ++j) wi_n[j] = Wih[(size_t)(128 + u) * 16 + j];
        #pragma unroll
        for (int c = 0; c < 2; ++c)
            #pragma unroll
            for (int jj = 0; jj < 8; ++jj) {
                int k = c * 32 + q * 8 + jj;
                float sn = 0.0f;
                #pragma unroll
                for (int j = 0; j < 16; ++j) sn = fmaf(wi_n[j], outW_l[j][k], sn);
                cin[c * 8 + jj] = sn;
            }
        split8(cin,      w1h[0], w1l[0]); split8(cin + 8,  w1h[1], w1l[1]);
        split8(wh_n,     w2h[0], w2l[0]); split8(wh_n + 8, w2h[1], w2l[1]);
        b_in = bih[u + 128];
        #pragma unroll
        for (int j = 0; j < 16; ++j) b_in = fmaf(outb[j], wi_n[j], b_in);
        b_hn = bhh[u + 128];
        #pragma unroll
        for (int i = 0; i < 4; ++i) {
            float sn = bih[u + 128];
            #pragma unroll
            for (int j = 0; j < 16; ++j)
                sn = fmaf(wi_n[j], init_l[q * 4 + i][j], sn);
            g3[i] = sn;
        }
        #pragma unroll
        for (int i = 0; i < 4; ++i)
            hold[i] = enc_h[(size_t)(b0 + q * 4 + i) * HDIM + u];
        if (wl == 7) {
            float ov[16];
            #pragma unroll
            for (int c = 0; c < 2; ++c)
                #pragma unroll
                for (int jj = 0; jj < 8; ++jj)
                    ov[c * 8 + jj] = outW_l[col][c * 32 + q * 8 + jj];
            split8(ov, owh[0], owl[0]); split8(ov + 8, owh[1], owl[1]);
            ob = outb[col];
        }
    }

    // ---- step 0 (unmerged r/z; gi0 from init via VALU) ----
    {
        const s8v ah0 = *(const s8v*)&hiL[0][col][q * 8];
        const s8v al0 = *(const s8v*)&loL[0][col][q * 8];
        const s8v ah1 = *(const s8v*)&hiL[0][col][32 + q * 8];
        const s8v al1 = *(const s8v*)&loL[0][col][32 + q * 8];
        f4v anh = z4;
        if (isG) {
            f4v a1, a2;
            a1 = MFMA16(ah0, s01h[0], z4);  a2 = MFMA16(ah0, s02h[0], z4);
            a1 = MFMA16(ah0, s01l[0], a1);  a2 = MFMA16(ah0, s02l[0], a2);
            a1 = MFMA16(al0, s01h[0], a1);  a2 = MFMA16(al0, s02h[0], a2);
            a1 = MFMA16(ah1, s01h[1], a1);  a2 = MFMA16(ah1, s02h[1], a2);
            a1 = MFMA16(ah1, s01l[1], a1);  a2 = MFMA16(ah1, s02l[1], a2);
            a1 = MFMA16(al1, s01h[1], a1);  a2 = MFMA16(al1, s02h[1], a2);
            #pragma unroll
            for (int i = 0; i < 4; ++i) {
                rsL[q * 4 + i][u] = sigmoidf_(a1[i] + g1[i]);
                zsL[q * 4 + i][u] = sigmoidf_(a2[i] + g2[i]);
            }
        } else {
            anh = MFMA16(ah0, w2h[0], z4);
            anh = MFMA16(ah0, w2l[0], anh);
            anh = MFMA16(al0, w2h[0], anh);
            anh = MFMA16(ah1, w2h[1], anh);
            anh = MFMA16(ah1, w2l[1], anh);
            anh = MFMA16(al1, w2h[1], anh);
        }
        lgkm_barrier();
        if (!isG) {
            unsigned short* hw = &hiL[1][q * 4][u];
            unsigned short* lw = &loL[1][q * 4][u];
            #pragma unroll
            for (int i = 0; i < 4; ++i) {
                float rs = rsL[q * 4 + i][u];
                float zs = zsL[q * 4 + i][u];
                float n  = tanhf_(g3[i] + rs * (anh[i] + b_hn));
                float h  = (1.0f - zs) * n + zs * hold[i];
                hold[i]  = h;
                h_split_store(h, hw + i * 72, lw + i * 72);
            }
        }
        lgkm_barrier();
    }

    // ---- steps 1..99 (merged weights); o_{t-1} by wl==7 ----
    for (int t = 1; t < SEQLEN; ++t) {
        const int cur = t & 1;
        const s8v ah0 = *(const s8v*)&hiL[cur][col][q * 8];
        const s8v al0 = *(const s8v*)&loL[cur][col][q * 8];
        const s8v ah1 = *(const s8v*)&hiL[cur][col][32 + q * 8];
        const s8v al1 = *(const s8v*)&loL[cur][col][32 + q * 8];

        f4v ain = z4, ahn = z4;
        if (isG) {
            f4v a1, a2;
            a1 = MFMA16(ah0, w1h[0], z4);  a2 = MFMA16(ah0, w2h[0], z4);
            a1 = MFMA16(ah0, w1l[0], a1);  a2 = MFMA16(ah0, w2l[0], a2);
            a1 = MFMA16(al0, w1h[0], a1);  a2 = MFMA16(al0, w2h[0], a2);
            a1 = MFMA16(ah1, w1h[1], a1);  a2 = MFMA16(ah1, w2h[1], a2);
            a1 = MFMA16(ah1, w1l[1], a1);  a2 = MFMA16(ah1, w2l[1], a2);
            a1 = MFMA16(al1, w1h[1], a1);  a2 = MFMA16(al1, w2h[1], a2);
            #pragma unroll
            for (int i = 0; i < 4; ++i) {
                rsL[q * 4 + i][u] = sigmoidf_(a1[i] + bias1);
                zsL[q * 4 + i][u] = sigmoidf_(a2[i] + bias2);
            }
        } else {
            ain = MFMA16(ah0, w1h[0], z4);  ahn = MFMA16(ah0, w2h[0], z4);
            ain = MFMA16(ah0, w1l[0], ain); ahn = MFMA16(ah0, w2l[0], ahn);
            ain = MFMA16(al0, w1h[0], ain); ahn = MFMA16(al0, w2h[0], ahn);
            ain = MFMA16(ah1, w1h[1], ain); ahn = MFMA16(ah1, w2h[1], ahn);
            ain = MFMA16(ah1, w1l[1], ain); ahn = MFMA16(ah1, w2l[1], ahn);
            ain = MFMA16(al1, w1h[1], ain); ahn = MFMA16(al1, w2h[1], ahn);
            if (wl == 7) {   // o_{t-1} = h_t @ outW^T + outb
                f4v oa;
                oa = MFMA16(ah0, owh[0], z4);
                oa = MFMA16(ah0, owl[0], oa);
                oa = MFMA16(al0, owh[0], oa);
                oa = MFMA16(ah1, owh[1], oa);
                oa = MFMA16(ah1, owl[1], oa);
                oa = MFMA16(al1, owh[1], oa);
                #pragma unroll
                for (int i = 0; i < 4; ++i)
                    dec_o[(((size_t)(b0 + q * 4 + i) * SEQLEN) + (t - 1)) * INDIM + col] = oa[i] + ob;
            }
        }
        lgkm_barrier();
        const int nxt = cur ^ 1;
        if (!isG) {
            unsigned short* hw = &hiL[nxt][q * 4][u];
            unsigned short* lw = &loL[nxt][q * 4][u];
            #pragma unroll
            for (int i = 0; i < 4; ++i) {
                float rs = rsL[q * 4 + i][u];
                float zs = zsL[q * 4 + i][u];
                float n  = tanhf_(ain[i] + b_in + rs * (ahn[i] + b_hn));
                float h  = (1.0f - zs) * n + zs * hold[i];
                hold[i]  = h;
                h_split_store(h, hw + i * 72, lw + i * 72);
            }
        }
        lgkm_barrier();
    }

    // ---- epilogue: o_99 from buf 0 (h_100) ----
    if (wl == 7) {
        const s8v ah0 = *(const s8v*)&hiL[0][col][q * 8];
        const s8v al0 = *(const s8v*)&loL[0][col][q * 8];
        const s8v ah1 = *(const s8v*)&hiL[0][col][32 + q * 8];
        const s8v al1 = *(const s8v*)&loL[0][col][32 + q * 8];
        f4v oa;
        oa = MFMA16(ah0, owh[0], z4);
        oa = MFMA16(ah0, owl[0], oa);
        oa = MFMA16(al0, owh[0], oa);
        oa = MFMA16(ah1, owh[1], oa);
        oa = MFMA16(ah1, owl[1], oa);
        oa = MFMA16(al1, owh[1], oa);
        #pragma unroll
        for (int i = 0; i < 4; ++i)
            dec_o[(((size_t)(b0 + q * 4 + i) * SEQLEN) + (SEQLEN - 1)) * INDIM + col] = oa[i] + ob;
    }
}

// =====================================================================
// Heads: 409600 independent rows; one thread per row. (unchanged)
// =====================================================================
__global__ void heads_kernel(
    const float* __restrict__ dec_o,
    const float* __restrict__ mW1, const float* __restrict__ mb1,
    const float* __restrict__ mW2, const float* __restrict__ mb2,
    const float* __restrict__ cW1, const float* __restrict__ cb1,
    const float* __restrict__ cW2, const float* __restrict__ cb2,
    float* __restrict__ out)
{
    const size_t r = (size_t)blockIdx.x * 256 + threadIdx.x;  // 0..409599

    float o16[16];
    {
        const float4* op = (const float4*)(dec_o + r * 16);
        #pragma unroll
        for (int c = 0; c < 4; ++c) {
            float4 v = op[c];
            o16[4 * c + 0] = v.x; o16[4 * c + 1] = v.y;
            o16[4 * c + 2] = v.z; o16[4 * c + 3] = v.w;
        }
    }

    float m[4], cv[10];
    #pragma unroll
    for (int j = 0; j < 4; ++j)  m[j]  = mb2[j];
    #pragma unroll
    for (int j = 0; j < 10; ++j) cv[j] = cb2[j];

    #pragma unroll 8
    for (int hu = 0; hu < 64; ++hu) {
        const float* w1m = mW1 + hu * 16;
        float hm = mb1[hu];
        #pragma unroll
        for (int i = 0; i < 16; ++i) hm = fmaf(w1m[i], o16[i], hm);
        float gm = gelu_exact(hm);
        #pragma unroll
        for (int j = 0; j < 4; ++j) m[j] = fmaf(mW2[j * 64 + hu], gm, m[j]);

        const float* w1c = cW1 + hu * 16;
        float hc = cb1[hu];
        #pragma unroll
        for (int i = 0; i < 16; ++i) hc = fmaf(w1c[i], o16[i], hc);
        float gc = gelu_exact(hc);
        #pragma unroll
        for (int j = 0; j < 10; ++j) cv[j] = fmaf(cW2[j * 64 + hu], gc, cv[j]);
    }

    m[2] = fminf(fmaxf(m[2], -1.0f), 1.0f);
    m[3] = fminf(fmaxf(m[3], -1.0f), 1.0f);

    float* means = out;
    float* covs  = out + MEANS_N;
    #pragma unroll
    for (int j = 0; j < 4; ++j)  means[r * 4 + j]  = m[j];
    #pragma unroll
    for (int j = 0; j < 10; ++j) covs[r * 10 + j]  = cv[j];
}

// =====================================================================
extern "C" void kernel_launch(void* const* d_in, const int* in_sizes, int n_in,
                              void* d_out, int out_size, void* d_ws, size_t ws_size,
                              hipStream_t stream)
{
    const float* x    = (const float*)d_in[0];
    const float* trg  = (const float*)d_in[1];
    const float* eWih = (const float*)d_in[2];
    const float* ebih = (const float*)d_in[3];
    const float* eWhh = (const float*)d_in[4];
    const float* ebhh = (const float*)d_in[5];
    const float* dWih = (const float*)d_in[6];
    const float* dbih = (const float*)d_in[7];
    const float* dWhh = (const float*)d_in[8];
    const float* dbhh = (const float*)d_in[9];
    const float* outW = (const float*)d_in[10];
    const float* outb = (const float*)d_in[11];
    const float* embW = (const float*)d_in[12];
    const float* embb = (const float*)d_in[13];
    const float* mW1  = (const float*)d_in[14];
    const float* mb1  = (const float*)d_in[15];
    const float* mW2  = (const float*)d_in[16];
    const float* mb2  = (const float*)d_in[17];
    const float* cW1  = (const float*)d_in[18];
    const float* cb1  = (const float*)d_in[19];
    const float* cW2  = (const float*)d_in[20];
    const float* cb2  = (const float*)d_in[21];

    float* ws    = (float*)d_ws;
    float* enc_h = ws;                          // 4096*64      = 262144 floats
    float* dec_o = ws + (size_t)BTOT * HDIM;    // 4096*100*16  = 6553600 floats
    float* outp  = (float*)d_out;

    enc_mfma_kernel<<<dim3(BTOT / 16), dim3(512), 0, stream>>>(x, eWih, ebih, eWhh, ebhh, enc_h);
    dec_mfma_kernel<<<dim3(BTOT / 16), dim3(512), 0, stream>>>(trg, dWih, dbih, dWhh, dbhh,
                                                               outW, outb, embW, embb, enc_h, dec_o);
    heads_kernel<<<dim3((BTOT * SEQLEN) / 256), dim3(256), 0, stream>>>(
        dec_o, mW1, mb1, mW2, mb2, cW1, cb1, cW2, cb2, outp);
}